// Round 1
// baseline (433.174 us; speedup 1.0000x reference)
//
#include <hip/hip_runtime.h>

#define V 8192
#define RPW 2          // rows of M per wave in the kinetic part
#define KBLOCKS (V / (RPW * 4))  // 1024 blocks, 4 waves each -> V/RPW waves

// ws layout (floats): [0]=kinetic raw sum, [1]=elastic sum, [2]=block-done counter (uint),
//                     [16..16+3V)=delta SoA
__global__ __launch_bounds__(256) void prep_kernel(
    const float* __restrict__ next_pos, const float* __restrict__ pos,
    const float* __restrict__ vel, const float* __restrict__ ext,
    const float* __restrict__ dt_p, float* __restrict__ ws) {
  int i = blockIdx.x * blockDim.x + threadIdx.x;
  if (i < 3) ws[i] = 0.f;  // zero accumulators + completion counter (ws is poisoned)
  if (i < V) {
    float dt = dt_p[0];
    float dt2 = dt * dt;
    float* dx = ws + 16;
    float* dy = dx + V;
    float* dz = dy + V;
    dx[i] = next_pos[3*i+0] - (pos[3*i+0] + vel[3*i+0]*dt + ext[3*i+0]*dt2);
    dy[i] = next_pos[3*i+1] - (pos[3*i+1] + vel[3*i+1]*dt + ext[3*i+1]*dt2);
    dz[i] = next_pos[3*i+2] - (pos[3*i+2] + vel[3*i+2]*dt + ext[3*i+2]*dt2);
  }
}

// One launch does elastic (first ceil(E/256) blocks, overlapped with the M stream),
// kinetic (all blocks), and the finalize (last block to finish).
// launch_bounds(256,4): >=4 waves/EU -> >=4 blocks/CU -> all 1024 blocks co-resident.
__global__ __launch_bounds__(256, 4) void main_kernel(
    const float* __restrict__ M, const float* __restrict__ next_pos,
    const int* __restrict__ elements, const float* __restrict__ poly,
    const float* __restrict__ measure, const float* __restrict__ lam,
    const float* __restrict__ mu, const float* __restrict__ dt_p,
    float* __restrict__ ws, float* __restrict__ out, int E) {
  const int t = threadIdx.x;
  const int lane = t & 63;
  const int wv = t >> 6;
  __shared__ float red[4];

  // ---------------- elastic: first ceil(E/256) blocks, one element/thread --------
  if ((int)blockIdx.x * 256 < E) {   // block-uniform branch
    int e = blockIdx.x * 256 + t;
    float contrib = 0.f;
    if (e < E) {
      float F00 = 0.f, F01 = 0.f, F02 = 0.f;
      float F10 = 0.f, F11 = 0.f, F12 = 0.f;
      float F20 = 0.f, F21 = 0.f, F22 = 0.f;
#pragma unroll
      for (int f = 0; f < 4; ++f) {
        int vi = elements[e * 4 + f];
        const float* p = next_pos + 3 * (size_t)vi;
        float px = p[0], py = p[1], pz = p[2];
        const float* b = poly + (size_t)e * 16 + f * 4;
        float b0 = b[0], b1 = b[1], b2 = b[2];
        F00 += px * b0; F01 += px * b1; F02 += px * b2;
        F10 += py * b0; F11 += py * b1; F12 += py * b2;
        F20 += pz * b0; F21 += pz * b1; F22 += pz * b2;
      }
      float Ic = F00*F00 + F01*F01 + F02*F02 +
                 F10*F10 + F11*F11 + F12*F12 +
                 F20*F20 + F21*F21 + F22*F22;
      float J = F00 * (F11 * F22 - F12 * F21)
              - F01 * (F10 * F22 - F12 * F20)
              + F02 * (F10 * F21 - F11 * F20);
      float l = lam[e], m = mu[e];
      float alpha = 0.75f * m / l + 1.f;  // (1 - 1/(3+1))*mu/lam + 1
      float Icv = fmaxf(Ic + 1.f, 0.f);
      float d = J - alpha;
      float psi = 0.5f * m * (Ic - 3.f) + 0.5f * l * d * d
                - 0.5f * m * logf(Icv + 1e-30f);
      contrib = psi * measure[e * 4 + 3];
    }
#pragma unroll
    for (int off = 32; off; off >>= 1) contrib += __shfl_down(contrib, off, 64);
    if (lane == 0) red[wv] = contrib;
    __syncthreads();
    if (t == 0) atomicAdd(ws + 1, red[0] + red[1] + red[2] + red[3]);
    __syncthreads();   // protect red[] before kinetic reuses it
  }

  // ---------------- kinetic: sum_{r,c} M[r,c]*(dx_r dx_c + dy_r dy_c + dz_r dz_c) --
  const float* __restrict__ dx = ws + 16;
  const float* __restrict__ dy = dx + V;
  const float* __restrict__ dz = dy + V;
  const float4* __restrict__ dx4 = (const float4*)dx;
  const float4* __restrict__ dy4 = (const float4*)dy;
  const float4* __restrict__ dz4 = (const float4*)dz;

  const int wave = blockIdx.x * 4 + wv;   // global wave id
  const int r0 = wave * RPW;

  // row-uniform delta components (hardware-broadcast same-address loads)
  float rx[RPW], ry[RPW], rz[RPW];
#pragma unroll
  for (int r = 0; r < RPW; ++r) {
    rx[r] = dx[r0 + r];
    ry[r] = dy[r0 + r];
    rz[r] = dz[r0 + r];
  }

  float a = 0.f;
#pragma unroll 2
  for (int i = 0; i < V / 4 / 64; ++i) {   // 32 iterations
    const int k = i * 64 + lane;           // float4 chunk index in the row
    const float4 cx = dx4[k];
    const float4 cy = dy4[k];
    const float4 cz = dz4[k];
#pragma unroll
    for (int r = 0; r < RPW; ++r) {
      const float4 m = *(const float4*)(M + (size_t)(r0 + r) * V + 4 * k);
      a += m.x * (rx[r]*cx.x + ry[r]*cy.x + rz[r]*cz.x);
      a += m.y * (rx[r]*cx.y + ry[r]*cy.y + rz[r]*cz.y);
      a += m.z * (rx[r]*cx.z + ry[r]*cy.z + rz[r]*cz.z);
      a += m.w * (rx[r]*cx.w + ry[r]*cy.w + rz[r]*cz.w);
    }
  }

  // 64-lane wave reduction
#pragma unroll
  for (int off = 32; off; off >>= 1) a += __shfl_down(a, off, 64);
  if (lane == 0) red[wv] = a;
  __syncthreads();

  if (t == 0) {
    atomicAdd(ws + 0, red[0] + red[1] + red[2] + red[3]);
    __threadfence();   // make this block's ws atomics visible device-wide
    unsigned done = atomicAdd((unsigned*)(ws + 2), 1u);
    if (done == gridDim.x - 1) {
      // last block: all other blocks' ws atomics ordered-before their counter inc.
      // Read sums via device-scope atomic read-back (L1 can't serve stale data).
      float kin_raw = atomicAdd(ws + 0, 0.f);
      float ela     = atomicAdd(ws + 1, 0.f);
      float dt = dt_p[0];
      float inv_h = 1.f / dt;
      float coeff = 0.5f * inv_h * inv_h;
      float kin = coeff * kin_raw;
      out[0] = kin + ela;
      out[1] = kin;
      out[2] = ela;
    }
  }
}

extern "C" void kernel_launch(void* const* d_in, const int* in_sizes, int n_in,
                              void* d_out, int out_size, void* d_ws, size_t ws_size,
                              hipStream_t stream) {
  const float* next_pos = (const float*)d_in[0];
  const float* pos      = (const float*)d_in[1];
  const float* vel      = (const float*)d_in[2];
  const float* ext      = (const float*)d_in[3];
  const float* M        = (const float*)d_in[4];
  const int*   elements = (const int*)d_in[5];
  const float* poly     = (const float*)d_in[6];
  const float* measure  = (const float*)d_in[7];
  const float* lam      = (const float*)d_in[8];
  const float* mu       = (const float*)d_in[9];
  const float* dt_p     = (const float*)d_in[10];
  float* out = (float*)d_out;
  float* ws  = (float*)d_ws;
  const int E = in_sizes[5] / 4;

  prep_kernel<<<(V + 255) / 256, 256, 0, stream>>>(next_pos, pos, vel, ext, dt_p, ws);
  main_kernel<<<KBLOCKS, 256, 0, stream>>>(M, next_pos, elements, poly, measure,
                                           lam, mu, dt_p, ws, out, E);
}

// Round 2
// 408.286 us; speedup vs baseline: 1.0610x; 1.0610x over previous
//
#include <hip/hip_runtime.h>

#define V 8192
#define RPW 2            // rows of M per wave in the kinetic kernel
#define CSPLIT 2         // column halves per row-pair (occupancy: 4096 -> 8192 waves)
#define KBLOCKS (V * CSPLIT / (RPW * 4))  // 2048 blocks, 4 waves each

// ws layout (floats): [0]=kinetic raw sum, [1]=elastic sum, [2]=elastic block-done
//                     counter (uint), [16..16+3V)=delta SoA
__global__ __launch_bounds__(256) void prep_kernel(
    const float* __restrict__ next_pos, const float* __restrict__ pos,
    const float* __restrict__ vel, const float* __restrict__ ext,
    const float* __restrict__ dt_p, float* __restrict__ ws) {
  int i = blockIdx.x * blockDim.x + threadIdx.x;
  if (i < 3) ws[i] = 0.f;  // zero accumulators + counter (ws is poisoned)
  if (i < V) {
    float dt = dt_p[0];
    float dt2 = dt * dt;
    float* dx = ws + 16;
    float* dy = dx + V;
    float* dz = dy + V;
    dx[i] = next_pos[3*i+0] - (pos[3*i+0] + vel[3*i+0]*dt + ext[3*i+0]*dt2);
    dy[i] = next_pos[3*i+1] - (pos[3*i+1] + vel[3*i+1]*dt + ext[3*i+1]*dt2);
    dz[i] = next_pos[3*i+2] - (pos[3*i+2] + vel[3*i+2]*dt + ext[3*i+2]*dt2);
  }
}

// kinetic raw sum: sum_{r,c} M[r,c] * (dx[r]dx[c] + dy[r]dy[c] + dz[r]dz[c])
// One wave owns RPW rows x one column half; lanes stride float4 across columns.
// NO min-waves launch_bounds: letting the compiler use ~60 VGPRs keeps the
// unroll-2 load pipeline (round-1 showed forcing occupancy -> 32 VGPR -> 850 GB/s).
__global__ __launch_bounds__(256) void kinetic_kernel(
    const float* __restrict__ M, const float* __restrict__ dsoa,
    float* __restrict__ acc) {
  const float* __restrict__ dx = dsoa;
  const float* __restrict__ dy = dsoa + V;
  const float* __restrict__ dz = dsoa + 2 * V;
  const float4* __restrict__ dx4 = (const float4*)dx;
  const float4* __restrict__ dy4 = (const float4*)dy;
  const float4* __restrict__ dz4 = (const float4*)dz;

  const int t = threadIdx.x;
  const int lane = t & 63;
  const int wv = t >> 6;
  const int wave = blockIdx.x * 4 + wv;       // 0 .. 8191
  const int r0 = (wave >> 1) * RPW;           // row pair
  const int kbase = (wave & 1) * (V / 4 / CSPLIT);  // column-half base (float4 units)

  // row-uniform delta components (hardware-broadcast same-address loads)
  float rx[RPW], ry[RPW], rz[RPW];
#pragma unroll
  for (int r = 0; r < RPW; ++r) {
    rx[r] = dx[r0 + r];
    ry[r] = dy[r0 + r];
    rz[r] = dz[r0 + r];
  }

  float a = 0.f;
#pragma unroll 2
  for (int i = 0; i < V / 4 / 64 / CSPLIT; ++i) {   // 16 iterations
    const int k = kbase + i * 64 + lane;            // float4 chunk index in the row
    const float4 cx = dx4[k];
    const float4 cy = dy4[k];
    const float4 cz = dz4[k];
#pragma unroll
    for (int r = 0; r < RPW; ++r) {
      const float4 m = *(const float4*)(M + (size_t)(r0 + r) * V + 4 * k);
      a += m.x * (rx[r]*cx.x + ry[r]*cy.x + rz[r]*cz.x);
      a += m.y * (rx[r]*cx.y + ry[r]*cy.y + rz[r]*cz.y);
      a += m.z * (rx[r]*cx.z + ry[r]*cy.z + rz[r]*cz.z);
      a += m.w * (rx[r]*cx.w + ry[r]*cy.w + rz[r]*cz.w);
    }
  }

  // 64-lane wave reduction
#pragma unroll
  for (int off = 32; off; off >>= 1) a += __shfl_down(a, off, 64);

  __shared__ float lds[4];
  if (lane == 0) lds[wv] = a;
  __syncthreads();
  if (t == 0) atomicAdd(acc, lds[0] + lds[1] + lds[2] + lds[3]);
}

// elastic energy + fused finalize (last elastic block to finish writes out[]).
// Kinetic's sum in ws[0] is visible here via the dispatch boundary (same stream).
__global__ __launch_bounds__(256) void elastic_kernel(
    const float* __restrict__ next_pos, const int* __restrict__ elements,
    const float* __restrict__ poly, const float* __restrict__ measure,
    const float* __restrict__ lam, const float* __restrict__ mu,
    const float* __restrict__ dt_p, float* __restrict__ ws,
    float* __restrict__ out, int E) {
  int e = blockIdx.x * blockDim.x + threadIdx.x;
  float contrib = 0.f;
  if (e < E) {
    float F00 = 0.f, F01 = 0.f, F02 = 0.f;
    float F10 = 0.f, F11 = 0.f, F12 = 0.f;
    float F20 = 0.f, F21 = 0.f, F22 = 0.f;
#pragma unroll
    for (int f = 0; f < 4; ++f) {
      int vi = elements[e * 4 + f];
      const float* p = next_pos + 3 * (size_t)vi;
      float px = p[0], py = p[1], pz = p[2];
      const float* b = poly + (size_t)e * 16 + f * 4;
      float b0 = b[0], b1 = b[1], b2 = b[2];
      F00 += px * b0; F01 += px * b1; F02 += px * b2;
      F10 += py * b0; F11 += py * b1; F12 += py * b2;
      F20 += pz * b0; F21 += pz * b1; F22 += pz * b2;
    }
    float Ic = F00*F00 + F01*F01 + F02*F02 +
               F10*F10 + F11*F11 + F12*F12 +
               F20*F20 + F21*F21 + F22*F22;
    float J = F00 * (F11 * F22 - F12 * F21)
            - F01 * (F10 * F22 - F12 * F20)
            + F02 * (F10 * F21 - F11 * F20);
    float l = lam[e], m = mu[e];
    float alpha = 0.75f * m / l + 1.f;  // (1 - 1/(3+1))*mu/lam + 1
    float Icv = fmaxf(Ic + 1.f, 0.f);
    float d = J - alpha;
    float psi = 0.5f * m * (Ic - 3.f) + 0.5f * l * d * d
              - 0.5f * m * logf(Icv + 1e-30f);
    contrib = psi * measure[e * 4 + 3];
  }
#pragma unroll
  for (int off = 32; off; off >>= 1) contrib += __shfl_down(contrib, off, 64);
  __shared__ float w[4];
  int lane = threadIdx.x & 63, wv = threadIdx.x >> 6;
  if (lane == 0) w[wv] = contrib;
  __syncthreads();
  if (threadIdx.x == 0) {
    atomicAdd(ws + 1, w[0] + w[1] + w[2] + w[3]);
    __threadfence();  // order our ws[1] add before the counter increment
    unsigned done = atomicAdd((unsigned*)(ws + 2), 1u);
    if (done == gridDim.x - 1) {
      // last elastic block: every block's ws[1] add is ordered before its
      // counter increment; read back via device-scope atomic RMWs.
      float ela     = atomicAdd(ws + 1, 0.f);
      float kin_raw = atomicAdd(ws + 0, 0.f);  // stable since kinetic dispatch ended
      float dt = dt_p[0];
      float inv_h = 1.f / dt;
      float coeff = 0.5f * inv_h * inv_h;
      float kin = coeff * kin_raw;
      out[0] = kin + ela;
      out[1] = kin;
      out[2] = ela;
    }
  }
}

extern "C" void kernel_launch(void* const* d_in, const int* in_sizes, int n_in,
                              void* d_out, int out_size, void* d_ws, size_t ws_size,
                              hipStream_t stream) {
  const float* next_pos = (const float*)d_in[0];
  const float* pos      = (const float*)d_in[1];
  const float* vel      = (const float*)d_in[2];
  const float* ext      = (const float*)d_in[3];
  const float* M        = (const float*)d_in[4];
  const int*   elements = (const int*)d_in[5];
  const float* poly     = (const float*)d_in[6];
  const float* measure  = (const float*)d_in[7];
  const float* lam      = (const float*)d_in[8];
  const float* mu       = (const float*)d_in[9];
  const float* dt_p     = (const float*)d_in[10];
  float* out = (float*)d_out;
  float* ws  = (float*)d_ws;
  const int E = in_sizes[5] / 4;

  prep_kernel<<<(V + 255) / 256, 256, 0, stream>>>(next_pos, pos, vel, ext, dt_p, ws);
  kinetic_kernel<<<KBLOCKS, 256, 0, stream>>>(M, ws + 16, ws);
  elastic_kernel<<<(E + 255) / 256, 256, 0, stream>>>(next_pos, elements, poly,
                                                      measure, lam, mu, dt_p,
                                                      ws, out, E);
}

// Round 3
// 390.453 us; speedup vs baseline: 1.1094x; 1.0457x over previous
//
#include <hip/hip_runtime.h>

#define V 8192
#define RPW 2          // rows of M per wave in the kinetic kernel
#define KBLOCKS (V / (RPW * 4))  // 1024 blocks, 4 waves each -> V/RPW waves

// ws layout (floats): [0]=kinetic raw sum, [1]=elastic sum, [2]=elastic block-done
//                     counter (uint), [16..16+3V)=delta SoA
__global__ __launch_bounds__(256) void prep_kernel(
    const float* __restrict__ next_pos, const float* __restrict__ pos,
    const float* __restrict__ vel, const float* __restrict__ ext,
    const float* __restrict__ dt_p, float* __restrict__ ws) {
  int i = blockIdx.x * blockDim.x + threadIdx.x;
  if (i < 3) ws[i] = 0.f;  // zero accumulators + counter (ws is poisoned)
  if (i < V) {
    float dt = dt_p[0];
    float dt2 = dt * dt;
    float* dx = ws + 16;
    float* dy = dx + V;
    float* dz = dy + V;
    dx[i] = next_pos[3*i+0] - (pos[3*i+0] + vel[3*i+0]*dt + ext[3*i+0]*dt2);
    dy[i] = next_pos[3*i+1] - (pos[3*i+1] + vel[3*i+1]*dt + ext[3*i+1]*dt2);
    dz[i] = next_pos[3*i+2] - (pos[3*i+2] + vel[3*i+2]*dt + ext[3*i+2]*dt2);
  }
}

// kinetic raw sum: sum_{r,c} M[r,c] * (dx[r]dx[c] + dy[r]dy[c] + dz[r]dz[c])
// EXACT round-0 known-good version (measured ~50 us standalone, ~5+ TB/s
// effective). One wave owns RPW rows; lanes stride float4 across all columns.
// Single scalar accumulator -> ~60 VGPRs, unroll-2 keeps loads pipelined.
// DO NOT add min-waves launch_bounds (r1: -> 32 VGPR, 850 GB/s) and DO NOT
// split columns across waves (r2: +25 us).
__global__ __launch_bounds__(256) void kinetic_kernel(
    const float* __restrict__ M, const float* __restrict__ dsoa,
    float* __restrict__ acc) {
  const float* __restrict__ dx = dsoa;
  const float* __restrict__ dy = dsoa + V;
  const float* __restrict__ dz = dsoa + 2 * V;
  const float4* __restrict__ dx4 = (const float4*)dx;
  const float4* __restrict__ dy4 = (const float4*)dy;
  const float4* __restrict__ dz4 = (const float4*)dz;

  const int t = threadIdx.x;
  const int lane = t & 63;
  const int wv = t >> 6;
  const int wave = blockIdx.x * 4 + wv;   // global wave id
  const int r0 = wave * RPW;

  // row-uniform delta components (hardware-broadcast same-address loads)
  float rx[RPW], ry[RPW], rz[RPW];
#pragma unroll
  for (int r = 0; r < RPW; ++r) {
    rx[r] = dx[r0 + r];
    ry[r] = dy[r0 + r];
    rz[r] = dz[r0 + r];
  }

  float a = 0.f;
#pragma unroll 2
  for (int i = 0; i < V / 4 / 64; ++i) {   // 32 iterations
    const int k = i * 64 + lane;           // float4 chunk index in the row
    const float4 cx = dx4[k];
    const float4 cy = dy4[k];
    const float4 cz = dz4[k];
#pragma unroll
    for (int r = 0; r < RPW; ++r) {
      const float4 m = *(const float4*)(M + (size_t)(r0 + r) * V + 4 * k);
      a += m.x * (rx[r]*cx.x + ry[r]*cy.x + rz[r]*cz.x);
      a += m.y * (rx[r]*cx.y + ry[r]*cy.y + rz[r]*cz.y);
      a += m.z * (rx[r]*cx.z + ry[r]*cy.z + rz[r]*cz.z);
      a += m.w * (rx[r]*cx.w + ry[r]*cy.w + rz[r]*cz.w);
    }
  }

  // 64-lane wave reduction
#pragma unroll
  for (int off = 32; off; off >>= 1) a += __shfl_down(a, off, 64);

  __shared__ float lds[4];
  if (lane == 0) lds[wv] = a;
  __syncthreads();
  if (t == 0) atomicAdd(acc, lds[0] + lds[1] + lds[2] + lds[3]);
}

// elastic energy + fused finalize (last elastic block to finish writes out[]).
// Kinetic's sum in ws[0] is stable here: the kinetic dispatch completed before
// this one starts (same stream).
__global__ __launch_bounds__(256) void elastic_kernel(
    const float* __restrict__ next_pos, const int* __restrict__ elements,
    const float* __restrict__ poly, const float* __restrict__ measure,
    const float* __restrict__ lam, const float* __restrict__ mu,
    const float* __restrict__ dt_p, float* __restrict__ ws,
    float* __restrict__ out, int E) {
  int e = blockIdx.x * blockDim.x + threadIdx.x;
  float contrib = 0.f;
  if (e < E) {
    float F00 = 0.f, F01 = 0.f, F02 = 0.f;
    float F10 = 0.f, F11 = 0.f, F12 = 0.f;
    float F20 = 0.f, F21 = 0.f, F22 = 0.f;
#pragma unroll
    for (int f = 0; f < 4; ++f) {
      int vi = elements[e * 4 + f];
      const float* p = next_pos + 3 * (size_t)vi;
      float px = p[0], py = p[1], pz = p[2];
      const float* b = poly + (size_t)e * 16 + f * 4;
      float b0 = b[0], b1 = b[1], b2 = b[2];
      F00 += px * b0; F01 += px * b1; F02 += px * b2;
      F10 += py * b0; F11 += py * b1; F12 += py * b2;
      F20 += pz * b0; F21 += pz * b1; F22 += pz * b2;
    }
    float Ic = F00*F00 + F01*F01 + F02*F02 +
               F10*F10 + F11*F11 + F12*F12 +
               F20*F20 + F21*F21 + F22*F22;
    float J = F00 * (F11 * F22 - F12 * F21)
            - F01 * (F10 * F22 - F12 * F20)
            + F02 * (F10 * F21 - F11 * F20);
    float l = lam[e], m = mu[e];
    float alpha = 0.75f * m / l + 1.f;  // (1 - 1/(3+1))*mu/lam + 1
    float Icv = fmaxf(Ic + 1.f, 0.f);
    float d = J - alpha;
    float psi = 0.5f * m * (Ic - 3.f) + 0.5f * l * d * d
              - 0.5f * m * logf(Icv + 1e-30f);
    contrib = psi * measure[e * 4 + 3];
  }
#pragma unroll
  for (int off = 32; off; off >>= 1) contrib += __shfl_down(contrib, off, 64);
  __shared__ float w[4];
  int lane = threadIdx.x & 63, wv = threadIdx.x >> 6;
  if (lane == 0) w[wv] = contrib;
  __syncthreads();
  if (threadIdx.x == 0) {
    atomicAdd(ws + 1, w[0] + w[1] + w[2] + w[3]);
    __threadfence();  // order our ws[1] add before the counter increment
    unsigned done = atomicAdd((unsigned*)(ws + 2), 1u);
    if (done == gridDim.x - 1) {
      // last elastic block: every block's ws[1] add is ordered before its
      // counter increment; read back via device-scope atomic RMWs.
      float ela     = atomicAdd(ws + 1, 0.f);
      float kin_raw = atomicAdd(ws + 0, 0.f);
      float dt = dt_p[0];
      float inv_h = 1.f / dt;
      float coeff = 0.5f * inv_h * inv_h;
      float kin = coeff * kin_raw;
      out[0] = kin + ela;
      out[1] = kin;
      out[2] = ela;
    }
  }
}

extern "C" void kernel_launch(void* const* d_in, const int* in_sizes, int n_in,
                              void* d_out, int out_size, void* d_ws, size_t ws_size,
                              hipStream_t stream) {
  const float* next_pos = (const float*)d_in[0];
  const float* pos      = (const float*)d_in[1];
  const float* vel      = (const float*)d_in[2];
  const float* ext      = (const float*)d_in[3];
  const float* M        = (const float*)d_in[4];
  const int*   elements = (const int*)d_in[5];
  const float* poly     = (const float*)d_in[6];
  const float* measure  = (const float*)d_in[7];
  const float* lam      = (const float*)d_in[8];
  const float* mu       = (const float*)d_in[9];
  const float* dt_p     = (const float*)d_in[10];
  float* out = (float*)d_out;
  float* ws  = (float*)d_ws;
  const int E = in_sizes[5] / 4;

  prep_kernel<<<(V + 255) / 256, 256, 0, stream>>>(next_pos, pos, vel, ext, dt_p, ws);
  kinetic_kernel<<<KBLOCKS, 256, 0, stream>>>(M, ws + 16, ws);
  elastic_kernel<<<(E + 255) / 256, 256, 0, stream>>>(next_pos, elements, poly,
                                                      measure, lam, mu, dt_p,
                                                      ws, out, E);
}